// Round 3
// baseline (259.171 us; speedup 1.0000x reference)
//
#include <hip/hip_runtime.h>

#define B_ 16
#define C_ 3
#define H_ 384
#define W_ 1280
#define HW_ (H_*W_)
#define EPS_ 1e-7f
#define ROWS_ 8   // rows per block-tile; H_ % ROWS_ == 0

__device__ __forceinline__ void mat3mul(const float* A, const float* Bm, float* C) {
  #pragma unroll
  for (int i = 0; i < 3; i++)
    #pragma unroll
    for (int j = 0; j < 3; j++)
      C[i*3+j] = A[i*3+0]*Bm[0*3+j] + A[i*3+1]*Bm[1*3+j] + A[i*3+2]*Bm[2*3+j];
}

// M = K * R * inv(K), T = K * t for batch b. ~100 flops, run by thread 0 of
// each block (cheaper than a separate dispatch + param round-trip).
__device__ void compute_MT(const float* __restrict__ pose,
                           const float* __restrict__ intr,
                           int b, float* M, float* T)
{
  float K[9];
  #pragma unroll
  for (int i = 0; i < 9; i++) K[i] = intr[b*9 + i];
  float aa0 = pose[b*6 + 0], aa1 = pose[b*6 + 1], aa2 = pose[b*6 + 2];
  float t0  = pose[b*6 + 3], t1  = pose[b*6 + 4], t2  = pose[b*6 + 5];

  float theta = sqrtf(aa0*aa0 + aa1*aa1 + aa2*aa2);
  float invn  = 1.0f / (theta + EPS_);
  float x = aa0*invn, y = aa1*invn, z = aa2*invn;
  float c = cosf(theta), s = sinf(theta), t = 1.0f - c;
  float R[9] = {
    t*x*x + c,   t*x*y - s*z, t*z*x + s*y,
    t*x*y + s*z, t*y*y + c,   t*y*z - s*x,
    t*z*x - s*y, t*y*z + s*x, t*z*z + c
  };

  float a = K[0], bb = K[1], cc = K[2];
  float d = K[3], e  = K[4], f  = K[5];
  float g = K[6], h  = K[7], ii = K[8];
  float A0 = e*ii - f*h, A1 = f*g - d*ii, A2 = d*h - e*g;
  float id = 1.0f / (a*A0 + bb*A1 + cc*A2);
  float iK[9] = {
    A0*id, (cc*h - bb*ii)*id, (bb*f - cc*e)*id,
    A1*id, (a*ii - cc*g)*id,  (cc*d - a*f)*id,
    A2*id, (bb*g - a*h)*id,   (a*e  - bb*d)*id
  };

  float KR[9];
  mat3mul(K, R, KR);
  mat3mul(KR, iK, M);
  T[0] = K[0]*t0 + K[1]*t1 + K[2]*t2;
  T[1] = K[3]*t0 + K[4]*t1 + K[5]*t2;
  T[2] = K[6]*t0 + K[7]*t1 + K[8]*t2;
}

__global__ __launch_bounds__(256) void warp_kernel(
    const float* __restrict__ src,
    const float* __restrict__ depth,
    const float* __restrict__ pose,
    const float* __restrict__ intr,
    float* __restrict__ out)
{
  __shared__ float sp[12];
  int b = blockIdx.z;
  if (threadIdx.x == 0) {
    float M[9], T[3];
    compute_MT(pose, intr, b, M, T);
    #pragma unroll
    for (int i = 0; i < 9; i++) sp[i] = M[i];
    #pragma unroll
    for (int i = 0; i < 3; i++) sp[9 + i] = T[i];
  }
  __syncthreads();
  float m00 = sp[0], m01 = sp[1], m02 = sp[2];
  float m10 = sp[3], m11 = sp[4], m12 = sp[5];
  float m20 = sp[6], m21 = sp[7], m22 = sp[8];
  float T0  = sp[9], T1  = sp[10], T2 = sp[11];

  int x    = blockIdx.x * 256 + threadIdx.x;   // W_ = 5*256 exact
  int row0 = blockIdx.y * ROWS_;               // H_ = 48*ROWS_ exact
  float xf = (float)x;

  // x-dependent parts hoisted out of the row loop
  float ax = m00*xf + m02;
  float bx = m10*xf + m12;
  float cxk = m20*xf + m22;

  size_t sb = (size_t)b * C_ * HW_;
  const float* s0 = src + sb;
  const float* s1 = s0 + HW_;
  const float* s2 = s1 + HW_;

  for (int r = 0; r < ROWS_; r++) {
    int i = row0 + r;
    float yf = (float)i;
    size_t pix = (size_t)b * HW_ + (size_t)i * W_ + x;

    float d = __builtin_nontemporal_load(&depth[pix]);   // streamed, no reuse

    float cx = (m01*yf + ax)*d + T0;
    float cy = (m11*yf + bx)*d + T1;
    float cz = (m21*yf + cxk)*d + T2;
    float zz = cz + EPS_;
    float inv = 1.0f / zz;
    float px = cx * inv;
    float py = cy * inv;

    float x0f = floorf(px), y0f = floorf(py);
    float x1f = x0f + 1.0f, y1f = y0f + 1.0f;
    float wx1 = px - x0f, wx0 = 1.0f - wx1;
    float wy1 = py - y0f, wy0 = 1.0f - wy1;

    float mx0 = (x0f >= 0.0f && x0f <= (float)(W_-1)) ? 1.0f : 0.0f;
    float mx1 = (x1f >= 0.0f && x1f <= (float)(W_-1)) ? 1.0f : 0.0f;
    float my0 = (y0f >= 0.0f && y0f <= (float)(H_-1)) ? 1.0f : 0.0f;
    float my1 = (y1f >= 0.0f && y1f <= (float)(H_-1)) ? 1.0f : 0.0f;

    int xc0 = (int)fminf(fmaxf(x0f, 0.0f), (float)(W_-1));
    int xc1 = (int)fminf(fmaxf(x1f, 0.0f), (float)(W_-1));
    int yc0 = (int)fminf(fmaxf(y0f, 0.0f), (float)(H_-1));
    int yc1 = (int)fminf(fmaxf(y1f, 0.0f), (float)(H_-1));

    int i00 = yc0*W_ + xc0;
    int i01 = yc0*W_ + xc1;
    int i10 = yc1*W_ + xc0;
    int i11 = yc1*W_ + xc1;

    float w00 = wx0*wy0*mx0*my0;
    float w01 = wx1*wy0*mx1*my0;
    float w10 = wx0*wy1*mx0*my1;
    float w11 = wx1*wy1*mx1*my1;

    size_t op = (size_t)i * W_ + x;
    float v0 = s0[i00]*w00 + s0[i01]*w01 + s0[i10]*w10 + s0[i11]*w11;
    float v1 = s1[i00]*w00 + s1[i01]*w01 + s1[i10]*w10 + s1[i11]*w11;
    float v2 = s2[i00]*w00 + s2[i01]*w01 + s2[i10]*w10 + s2[i11]*w11;
    __builtin_nontemporal_store(v0, &out[sb + op]);
    __builtin_nontemporal_store(v1, &out[sb + HW_ + op]);
    __builtin_nontemporal_store(v2, &out[sb + 2*(size_t)HW_ + op]);
  }
}

extern "C" void kernel_launch(void* const* d_in, const int* in_sizes, int n_in,
                              void* d_out, int out_size, void* d_ws, size_t ws_size,
                              hipStream_t stream) {
  const float* src   = (const float*)d_in[0];
  const float* depth = (const float*)d_in[1];
  const float* pose  = (const float*)d_in[2];
  const float* intr  = (const float*)d_in[3];
  float* out = (float*)d_out;

  dim3 grid(W_ / 256, H_ / ROWS_, B_);
  warp_kernel<<<grid, 256, 0, stream>>>(src, depth, pose, intr, out);
}

// Round 4
// 238.905 us; speedup vs baseline: 1.0848x; 1.0848x over previous
//
#include <hip/hip_runtime.h>

#define B_ 16
#define C_ 3
#define H_ 384
#define W_ 1280
#define HW_ (H_*W_)
#define EPS_ 1e-7f

typedef float v2f __attribute__((ext_vector_type(2)));

// 8-byte load at 4-byte alignment — gfx950 global loads support this in HW;
// goal is a single global_load_dwordx2 (1 cache-line touch for the x-pair
// instead of 2 separate dword gathers).
__device__ __forceinline__ v2f load2(const float* p) {
  v2f r;
  __builtin_memcpy(&r, p, 8);
  return r;
}

__device__ __forceinline__ void mat3mul(const float* A, const float* Bm, float* C) {
  #pragma unroll
  for (int i = 0; i < 3; i++)
    #pragma unroll
    for (int j = 0; j < 3; j++)
      C[i*3+j] = A[i*3+0]*Bm[0*3+j] + A[i*3+1]*Bm[1*3+j] + A[i*3+2]*Bm[2*3+j];
}

// M = K * R * inv(K), T = K * t for batch b.
__device__ void compute_MT(const float* __restrict__ pose,
                           const float* __restrict__ intr,
                           int b, float* M, float* T)
{
  float K[9];
  #pragma unroll
  for (int i = 0; i < 9; i++) K[i] = intr[b*9 + i];
  float aa0 = pose[b*6 + 0], aa1 = pose[b*6 + 1], aa2 = pose[b*6 + 2];
  float t0  = pose[b*6 + 3], t1  = pose[b*6 + 4], t2  = pose[b*6 + 5];

  float theta = sqrtf(aa0*aa0 + aa1*aa1 + aa2*aa2);
  float invn  = 1.0f / (theta + EPS_);
  float x = aa0*invn, y = aa1*invn, z = aa2*invn;
  float c = cosf(theta), s = sinf(theta), t = 1.0f - c;
  float R[9] = {
    t*x*x + c,   t*x*y - s*z, t*z*x + s*y,
    t*x*y + s*z, t*y*y + c,   t*y*z - s*x,
    t*z*x - s*y, t*y*z + s*x, t*z*z + c
  };

  float a = K[0], bb = K[1], cc = K[2];
  float d = K[3], e  = K[4], f  = K[5];
  float g = K[6], h  = K[7], ii = K[8];
  float A0 = e*ii - f*h, A1 = f*g - d*ii, A2 = d*h - e*g;
  float id = 1.0f / (a*A0 + bb*A1 + cc*A2);
  float iK[9] = {
    A0*id, (cc*h - bb*ii)*id, (bb*f - cc*e)*id,
    A1*id, (a*ii - cc*g)*id,  (cc*d - a*f)*id,
    A2*id, (bb*g - a*h)*id,   (a*e  - bb*d)*id
  };

  float KR[9];
  mat3mul(K, R, KR);
  mat3mul(KR, iK, M);
  T[0] = K[0]*t0 + K[1]*t1 + K[2]*t2;
  T[1] = K[3]*t0 + K[4]*t1 + K[5]*t2;
  T[2] = K[6]*t0 + K[7]*t1 + K[8]*t2;
}

__global__ __launch_bounds__(256) void warp_kernel(
    const float* __restrict__ src,
    const float* __restrict__ depth,
    const float* __restrict__ pose,
    const float* __restrict__ intr,
    float* __restrict__ out)
{
  __shared__ float sp[12];
  int b = blockIdx.y;
  if (threadIdx.x == 0) {
    float M[9], T[3];
    compute_MT(pose, intr, b, M, T);
    #pragma unroll
    for (int i = 0; i < 9; i++) sp[i] = M[i];
    #pragma unroll
    for (int i = 0; i < 3; i++) sp[9 + i] = T[i];
  }
  __syncthreads();
  float m00 = sp[0], m01 = sp[1], m02 = sp[2];
  float m10 = sp[3], m11 = sp[4], m12 = sp[5];
  float m20 = sp[6], m21 = sp[7], m22 = sp[8];
  float T0  = sp[9], T1  = sp[10], T2 = sp[11];

  int p = blockIdx.x * 256 + threadIdx.x;   // HW_ divisible by 256
  int j = p % W_;
  int i = p / W_;

  float d  = depth[(size_t)b * HW_ + p];
  float xf = (float)j, yf = (float)i;

  float cx = (m00*xf + m01*yf + m02)*d + T0;
  float cy = (m10*xf + m11*yf + m12)*d + T1;
  float cz = (m20*xf + m21*yf + m22)*d + T2;
  float inv = 1.0f / (cz + EPS_);
  float px = cx * inv;
  float py = cy * inv;

  float x0f = floorf(px), y0f = floorf(py);
  float x1f = x0f + 1.0f, y1f = y0f + 1.0f;
  float wx1 = px - x0f, wx0 = 1.0f - wx1;
  float wy1 = py - y0f, wy0 = 1.0f - wy1;

  float mx0 = (x0f >= 0.0f && x0f <= (float)(W_-1)) ? 1.0f : 0.0f;
  float mx1 = (x1f >= 0.0f && x1f <= (float)(W_-1)) ? 1.0f : 0.0f;
  float my0 = (y0f >= 0.0f && y0f <= (float)(H_-1)) ? 1.0f : 0.0f;
  float my1 = (y1f >= 0.0f && y1f <= (float)(H_-1)) ? 1.0f : 0.0f;

  int xc0 = (int)fminf(fmaxf(x0f, 0.0f), (float)(W_-1));
  int xc1 = (int)fminf(fmaxf(x1f, 0.0f), (float)(W_-1));
  int yc0 = (int)fminf(fmaxf(y0f, 0.0f), (float)(H_-1));
  int yc1 = (int)fminf(fmaxf(y1f, 0.0f), (float)(H_-1));

  float w00 = wx0*wy0*mx0*my0;
  float w01 = wx1*wy0*mx1*my0;
  float w10 = wx0*wy1*mx0*my1;
  float w11 = wx1*wy1*mx1*my1;

  // x-pair merge: one 8B load covers both taps of a row.
  // base = min(xc0, W-2); xc0,xc1 ∈ {base, base+1} in ALL clamp cases:
  //   interior:        xc0=base,   xc1=base+1
  //   left-clamp:      xc0=xc1=base(=0)
  //   right-edge/OOB:  xc0=xc1=base+1(=W-1)
  int base = xc0 < (W_-2) ? xc0 : (W_-2);
  bool s0 = (xc0 == base);     // xc0 tap lives in lane .x
  bool s1 = (xc1 == base + 1); // xc1 tap lives in lane .y
  float wax = (s0 ? w00 : 0.0f) + (s1 ? 0.0f : w01);
  float way = (s0 ? 0.0f : w00) + (s1 ? w01 : 0.0f);
  float wbx = (s0 ? w10 : 0.0f) + (s1 ? 0.0f : w11);
  float wby = (s0 ? 0.0f : w10) + (s1 ? w11 : 0.0f);

  int rb0 = yc0*W_ + base;
  int rb1 = yc1*W_ + base;

  size_t sb = (size_t)b * C_ * HW_;
  size_t op = (size_t)p;
  const float* s0p = src + sb;
  const float* s1p = s0p + HW_;
  const float* s2p = s1p + HW_;

  v2f a0 = load2(s0p + rb0);
  v2f b0 = load2(s0p + rb1);
  v2f a1 = load2(s1p + rb0);
  v2f b1 = load2(s1p + rb1);
  v2f a2 = load2(s2p + rb0);
  v2f b2 = load2(s2p + rb1);

  float v0 = a0.x*wax + a0.y*way + b0.x*wbx + b0.y*wby;
  float v1 = a1.x*wax + a1.y*way + b1.x*wbx + b1.y*wby;
  float v2 = a2.x*wax + a2.y*way + b2.x*wbx + b2.y*wby;

  __builtin_nontemporal_store(v0, &out[sb + op]);
  __builtin_nontemporal_store(v1, &out[sb + HW_ + op]);
  __builtin_nontemporal_store(v2, &out[sb + 2*(size_t)HW_ + op]);
}

extern "C" void kernel_launch(void* const* d_in, const int* in_sizes, int n_in,
                              void* d_out, int out_size, void* d_ws, size_t ws_size,
                              hipStream_t stream) {
  const float* src   = (const float*)d_in[0];
  const float* depth = (const float*)d_in[1];
  const float* pose  = (const float*)d_in[2];
  const float* intr  = (const float*)d_in[3];
  float* out = (float*)d_out;

  dim3 grid(HW_ / 256, B_);
  warp_kernel<<<grid, 256, 0, stream>>>(src, depth, pose, intr, out);
}